// Round 1
// baseline (1232.324 us; speedup 1.0000x reference)
//
#include <hip/hip_runtime.h>

// Outputs (concatenated flat in d_out, all float32):
//   loss     [B*16]      = (x - y)^2
//   d_loss   [B*16]      = 2*(x - y)
//   sqd_loss [B*16*16]   = per-sample Hessian = 2*I_16 (input-independent)

__global__ __launch_bounds__(256) void loss_grad_kernel(
    const float4* __restrict__ x,
    const float4* __restrict__ y,
    float4* __restrict__ loss,
    float4* __restrict__ dloss,
    int n4) {
    int i = blockIdx.x * blockDim.x + threadIdx.x;
    if (i >= n4) return;
    float4 a = x[i];
    float4 b = y[i];
    float4 d;
    d.x = a.x - b.x;
    d.y = a.y - b.y;
    d.z = a.z - b.z;
    d.w = a.w - b.w;
    float4 l;
    l.x = d.x * d.x;
    l.y = d.y * d.y;
    l.z = d.z * d.z;
    l.w = d.w * d.w;
    float4 g;
    g.x = 2.0f * d.x;
    g.y = 2.0f * d.y;
    g.z = 2.0f * d.z;
    g.w = 2.0f * d.w;
    loss[i] = l;
    dloss[i] = g;
}

// Fill sqd_loss with 2*I_16 per 256-element block.
// Flat float index f: row = (f>>4)&15, col = f&15. A float4 at base f
// (f%4==0) has col in {0,4,8,12}, so all 4 elements share the same row.
__global__ __launch_bounds__(256) void hess_fill_kernel(
    float4* __restrict__ out, unsigned int n4) {
    unsigned int i = blockIdx.x * blockDim.x + threadIdx.x;
    if (i >= n4) return;
    unsigned int f = i << 2;                 // flat float index
    unsigned int col = f & 15u;              // 0,4,8,12
    unsigned int row = (f >> 4) & 15u;
    float4 v;
    v.x = (row == col)      ? 2.0f : 0.0f;
    v.y = (row == col + 1u) ? 2.0f : 0.0f;
    v.z = (row == col + 2u) ? 2.0f : 0.0f;
    v.w = (row == col + 3u) ? 2.0f : 0.0f;
    out[i] = v;
}

extern "C" void kernel_launch(void* const* d_in, const int* in_sizes, int n_in,
                              void* d_out, int out_size, void* d_ws, size_t ws_size,
                              hipStream_t stream) {
    const float* model_out = (const float*)d_in[0];
    const float* y_true    = (const float*)d_in[1];
    float* out = (float*)d_out;

    const int BD = in_sizes[0];              // B*16 = 16,777,216
    float* loss_p  = out;                    // [BD]
    float* dloss_p = out + BD;               // [BD]
    float* sqd_p   = out + 2 * (size_t)BD;   // [BD*16]

    // Kernel 1: fused loss + d_loss (float4 vectorized)
    {
        int n4 = BD / 4;                     // 4,194,304
        int block = 256;
        int grid = (n4 + block - 1) / block; // 16384
        loss_grad_kernel<<<grid, block, 0, stream>>>(
            (const float4*)model_out, (const float4*)y_true,
            (float4*)loss_p, (float4*)dloss_p, n4);
    }

    // Kernel 2: Hessian pattern fill (float4 vectorized, write-only)
    {
        unsigned int n4 = (unsigned int)((size_t)BD * 16 / 4); // 67,108,864
        int block = 256;
        unsigned int grid = (n4 + block - 1) / block;          // 262,144
        hess_fill_kernel<<<grid, block, 0, stream>>>((float4*)sqd_p, n4);
    }
}